// Round 11
// baseline (846.319 us; speedup 1.0000x reference)
//
#include <hip/hip_runtime.h>

// ---------------------------------------------------------------------------
// SeparateWindowedValuesCoordinatesAttention  (B=2, H=W=224, VD=512, CD=128,
// INNER=512, NH=8, E=64, WS=8, Wh=Ww=28; no padding since 224%8==0)
//
// R11: GEMM = 256x256 tile, 8 waves (2Mx4N, per-wave 128x64), BK=32,
// double-buffered 64 KB LDS, R7's proven 2-barrier schedule and 64-B-row
// zero-conflict XOR swizzle (R10's 128-B rows broke bank balance -> 1.4e7
// conflicts; R10's coarse asm pipeline at 1 block/CU bought nothing).
// 2 blocks/CU restores cross-block latency hiding; 32 MFMA per barrier
// (2x R7 amortization). attn unchanged from R9.
// ---------------------------------------------------------------------------

using u16 = unsigned short;
typedef short bf16x8 __attribute__((ext_vector_type(8)));   // MFMA A/B frag (8 bf16)
typedef float f32x4 __attribute__((ext_vector_type(4)));    // MFMA C/D frag
typedef u16 u16x4 __attribute__((ext_vector_type(4)));
typedef u16 u16x8 __attribute__((ext_vector_type(8)));

__device__ __forceinline__ float bf2f(u16 v) {
  return __uint_as_float(((unsigned)v) << 16);
}
__device__ __forceinline__ u16 f2bf(float f) {   // round-to-nearest-even
  unsigned u = __float_as_uint(f);
  u += 0x7fffu + ((u >> 16) & 1u);
  return (u16)(u >> 16);
}

// async global->LDS, 16 bytes per lane.
__device__ __forceinline__ void gld16(const u16* g, u16* l) {
  __builtin_amdgcn_global_load_lds(
      (const __attribute__((address_space(1))) unsigned*)g,
      (__attribute__((address_space(3))) unsigned*)l, 16, 0, 0);
}

struct f8 { float v[8]; };
__device__ __forceinline__ f8 ld8(const float* p) {
  f8 r;
  *(float4*)&r.v[0] = *(const float4*)p;
  *(float4*)&r.v[4] = *(const float4*)(p + 4);
  return r;
}
__device__ __forceinline__ bf16x8 nfrag(u16x8 raw, const f8& A, const f8& B, float s) {
  u16x8 o;
#pragma unroll
  for (int j = 0; j < 8; ++j) o[j] = f2bf(bf2f(raw[j]) * (A.v[j] * s + B.v[j]));
  return *(bf16x8*)&o;
}
__device__ __forceinline__ bf16x8 nfragA(u16x8 raw, const f8& A, float s) {
  u16x8 o;
#pragma unroll
  for (int j = 0; j < 8; ++j) o[j] = f2bf(bf2f(raw[j]) * (A.v[j] * s));
  return *(bf16x8*)&o;
}

// ---------------------------------------------------------------------------
// prep kernels
// ---------------------------------------------------------------------------
__global__ void conv_bf16(const float* __restrict__ in, u16* __restrict__ out) {
  size_t i = ((size_t)blockIdx.x * 256 + threadIdx.x) * 8;
  float4 a = *(const float4*)(in + i);
  float4 b = *(const float4*)(in + i + 4);
  u16x8 o;
  o[0] = f2bf(a.x); o[1] = f2bf(a.y); o[2] = f2bf(a.z); o[3] = f2bf(a.w);
  o[4] = f2bf(b.x); o[5] = f2bf(b.y); o[6] = f2bf(b.z); o[7] = f2bf(b.w);
  *(u16x8*)(out + i) = o;
}

__global__ void prep_wv(const float* __restrict__ Wqkv, const float* __restrict__ Wv,
                        u16* __restrict__ out) {
  int idx = blockIdx.x * 256 + threadIdx.x;
  if (idx >= 1536 * 512) return;
  int j = idx >> 9, kk = idx & 511;
  int t = j >> 9, rr = j & 511, nn = rr >> 6, e = rr & 63;
  int cc = 3 * (e * 8 + nn) + t;
  float v = (cc < 1024) ? Wqkv[kk * 1024 + cc] : Wv[kk * 512 + (cc - 1024)];
  out[idx] = f2bf(v);
}

__global__ void prep_wc(const float* __restrict__ W, u16* __restrict__ out) {
  int idx = blockIdx.x * 256 + threadIdx.x;
  if (idx >= 1024 * 128) return;
  int j = idx >> 7, kk = idx & 127;
  int t = j >> 9, rr = j & 511, nn = rr >> 6, e = rr & 63;
  int cc = 2 * (e * 8 + nn) + t;
  out[idx] = f2bf(W[kk * 1024 + cc]);
}

__global__ void prep_wout(const float* __restrict__ W, u16* __restrict__ out) {
  int idx = blockIdx.x * 256 + threadIdx.x;
  if (idx >= 512 * 512) return;
  int o = idx >> 9, kk = idx & 511;
  out[idx] = f2bf(W[kk * 512 + o]);
}

__global__ void prep_vec(const float* __restrict__ bqkv, const float* __restrict__ g_v,
                         const float* __restrict__ bv, const float* __restrict__ bqkc,
                         const float* __restrict__ g_c,
                         float* __restrict__ bpv, float* __restrict__ gAv, float* __restrict__ gBv,
                         float* __restrict__ bpc, float* __restrict__ gAc, float* __restrict__ gBc) {
  int j = blockIdx.x * 256 + threadIdx.x;
  if (j < 1536) {
    int t = j >> 9, rr = j & 511, nn = rr >> 6, e = rr & 63;
    int cc = 3 * (e * 8 + nn) + t;
    if (cc < 1024) { bpv[j] = bqkv[cc]; gAv[j] = g_v[cc]; gBv[j] = 0.f; }
    else           { bpv[j] = bv[cc - 1024]; gAv[j] = 0.f; gBv[j] = 1.f; }
  }
  if (j < 1024) {
    int t = j >> 9, rr = j & 511, nn = rr >> 6, e = rr & 63;
    int cc = 2 * (e * 8 + nn) + t;
    bpc[j] = bqkc[cc]; gAc[j] = g_c[cc]; gBc[j] = 0.f;
  }
}

__global__ void prep_biasT(const float* __restrict__ pe, float* __restrict__ bT) {
  int idx = blockIdx.x * 256 + threadIdx.x;
  if (idx >= 4 * 4096) return;
  int v = idx >> 12, q = (idx >> 6) & 63, p = idx & 63;
  int ap = p >> 3, bp = p & 7, aq = q >> 3, bq = q & 7;
  float val = pe[(aq - ap + 7) * 15 + (bq - bp + 7)];
  if ((v & 1) && ((ap >= 4) != (aq >= 4))) val = -1e30f;   // ROW_MASK (wi==27)
  if ((v & 2) && ((bp >= 4) != (bq >= 4))) val = -1e30f;   // COL_MASK (wj==27)
  bT[idx] = val;
}

// ---------------------------------------------------------------------------
// GEMM: C[M=100352][N] = A[M][K] * Bt[N][K]^T + bias   (A, Bt both bf16)
// 256x256 tile, 8 waves (wr=wid>>2 picks 128 A-rows, wc=wid&3 picks 64
// B-cols), BK=32, double-buffered LDS [2][256][32] per matrix (64 KB total),
// global_load_lds width-16 staging with R7's XOR swizzle
// (chunk ^ ((row>>1)&3), 64-B rows -> balanced banks, 0 conflicts),
// one barrier per K-step. Lane (g,c), frag (mi 0..7, ni 0..3), reg r holds
//   C[bm*256 + wr*128 + mi*16 + c][bn*256 + wc*64 + ni*16 + g*4 + r]
// MODE 0: bf16 out + sumsq partials (stride N/256). MODE 1: f32 out.
// ---------------------------------------------------------------------------
template<int N, int K, int MODE>
__global__ __launch_bounds__(512, 2) void gemm_bt(
    const u16* __restrict__ A, const u16* __restrict__ Bt,
    const float* __restrict__ bias, void* __restrict__ outp,
    float* __restrict__ part, const float* __restrict__ gB, int nwg) {
  constexpr int NCB = N / 256;
  constexpr int KT = K / 32;
  const int orig = blockIdx.x;
  const int work = (orig & 7) * (nwg >> 3) + (orig >> 3);   // XCD swizzle
  const int bm = work / NCB, bn = work % NCB;

  const int tid = threadIdx.x;          // 0..511
  const int wid = tid >> 6;
  const int lane = tid & 63;
  const int wr = wid >> 2, wc = wid & 3;
  const int g = lane >> 4, c = lane & 15;

  __shared__ u16 As[2 * 8192];          // [buf][256 rows][32 cols]  32 KB
  __shared__ u16 Bs[2 * 8192];          // 32 KB

  f32x4 acc[8][4] = {};
  const u16* Ag = A + (size_t)bm * 256 * K;
  const u16* Bg = Bt + (size_t)bn * 256 * K;

  auto stage = [&](int buf, int kt) {   // 4 gld16 per thread
    const int k0 = kt * 32;
#pragma unroll
    for (int i = 0; i < 2; ++i) {
      const int idx = i * 512 + tid;              // 0..1023
      const int row = idx >> 2, ch = idx & 3;
      const int sch = ch ^ ((row >> 1) & 3);      // inverse-swizzled source
      gld16(Ag + (size_t)row * K + k0 + sch * 8, As + buf * 8192 + idx * 8);
      gld16(Bg + (size_t)row * K + k0 + sch * 8, Bs + buf * 8192 + idx * 8);
    }
  };

  stage(0, 0);
  __syncthreads();

  const int swz = (c >> 1) & 3;         // (row>>1)&3 for row = base16 + c
  for (int kt = 0; kt < KT; ++kt) {
    if (kt + 1 < KT) stage((kt + 1) & 1, kt + 1);
    const u16* Ab = As + (kt & 1) * 8192;
    const u16* Bb = Bs + (kt & 1) * 8192;
    bf16x8 af[8], bfv[4];
#pragma unroll
    for (int mi = 0; mi < 8; ++mi)
      af[mi] = *(const bf16x8*)(Ab + (wr * 128 + mi * 16 + c) * 32 + (g ^ swz) * 8);
#pragma unroll
    for (int ni = 0; ni < 4; ++ni)
      bfv[ni] = *(const bf16x8*)(Bb + (wc * 64 + ni * 16 + c) * 32 + (g ^ swz) * 8);
#pragma unroll
    for (int mi = 0; mi < 8; ++mi)
#pragma unroll
      for (int ni = 0; ni < 4; ++ni)
        acc[mi][ni] = __builtin_amdgcn_mfma_f32_16x16x32_bf16(bfv[ni], af[mi], acc[mi][ni], 0, 0, 0);
    __syncthreads();
  }

  const int rowbase = bm * 256 + wr * 128;
  const int colbase = bn * 256 + wc * 64;
  if constexpr (MODE == 0) {
    u16* O = (u16*)outp;
    float rowsq[8];
#pragma unroll
    for (int mi = 0; mi < 8; ++mi) rowsq[mi] = 0.f;
#pragma unroll
    for (int ni = 0; ni < 4; ++ni) {
      const int col4 = colbase + ni * 16 + g * 4;
      const float4 bb = *(const float4*)(bias + col4);
      const float4 gb = *(const float4*)(gB + col4);
#pragma unroll
      for (int mi = 0; mi < 8; ++mi) {
        const int row = rowbase + mi * 16 + c;
        u16x4 pk;
        float v0 = acc[mi][ni][0] + bb.x;
        float v1 = acc[mi][ni][1] + bb.y;
        float v2 = acc[mi][ni][2] + bb.z;
        float v3 = acc[mi][ni][3] + bb.w;
        pk[0] = f2bf(v0); pk[1] = f2bf(v1); pk[2] = f2bf(v2); pk[3] = f2bf(v3);
        *(u16x4*)(O + (size_t)row * N + col4) = pk;
        rowsq[mi] += (gb.x == 0.f ? v0 * v0 : 0.f) + (gb.y == 0.f ? v1 * v1 : 0.f)
                   + (gb.z == 0.f ? v2 * v2 : 0.f) + (gb.w == 0.f ? v3 * v3 : 0.f);
      }
    }
#pragma unroll
    for (int mi = 0; mi < 8; ++mi) {
      float s = rowsq[mi];
      s += __shfl_xor(s, 16);
      s += __shfl_xor(s, 32);
      rowsq[mi] = s;
    }
    __syncthreads();
    float* red = (float*)As;             // [4][256]
    if (g == 0) {
#pragma unroll
      for (int mi = 0; mi < 8; ++mi)
        red[wc * 256 + wr * 128 + mi * 16 + c] = rowsq[mi];
    }
    __syncthreads();
    if (tid < 256)
      part[(size_t)(bm * 256 + tid) * NCB + bn] =
          red[tid] + red[256 + tid] + red[512 + tid] + red[768 + tid];
  } else {
    float* O = (float*)outp;
#pragma unroll
    for (int ni = 0; ni < 4; ++ni) {
      const int col4 = colbase + ni * 16 + g * 4;
      const float4 bb = *(const float4*)(bias + col4);
#pragma unroll
      for (int mi = 0; mi < 8; ++mi) {
        const int row = rowbase + mi * 16 + c;
        f32x4 o;
        o[0] = acc[mi][ni][0] + bb.x;
        o[1] = acc[mi][ni][1] + bb.y;
        o[2] = acc[mi][ni][2] + bb.z;
        o[3] = acc[mi][ni][3] + bb.w;
        *(f32x4*)(O + (size_t)row * N + col4) = o;
      }
    }
  }
}

// ---------------------------------------------------------------------------
__global__ void combine_scales(const float* __restrict__ pvp, const float* __restrict__ pcp,
                               float* __restrict__ sv, float* __restrict__ sc) {
  const int i = blockIdx.x * 256 + threadIdx.x;  // exact 100352
  float s = 0.f;
#pragma unroll
  for (int k = 0; k < 6; ++k) s += pvp[(size_t)i * 6 + k];
  sv[i] = rsqrtf(s * (1.f / 1024.f) + 1e-6f);
  float s2 = 0.f;
#pragma unroll
  for (int k = 0; k < 4; ++k) s2 += pcp[(size_t)i * 4 + k];
  sc[i] = rsqrtf(s2 * (1.f / 1024.f) + 1e-6f);
}

// ---------------------------------------------------------------------------
// attention (unchanged from R9): one wave per (batch, head, window);
// K/Q fragments direct from global with inline rmsnorm; LDS only for P and V.
// ---------------------------------------------------------------------------
__global__ __launch_bounds__(64) void attn_kernel(
    const u16* __restrict__ Pv, const u16* __restrict__ Pc,
    const float* __restrict__ sv, const float* __restrict__ sc,
    const float* __restrict__ gAv, const float* __restrict__ gBv,
    const float* __restrict__ gAc, const float* __restrict__ gBc,
    const float* __restrict__ biasT, u16* __restrict__ Y) {
  const int l = threadIdx.x;
  int bx = blockIdx.x;
  const int wj = bx % 28; bx /= 28;
  const int wi = bx % 28; bx /= 28;
  const int n = bx & 7;
  const int bi = bx >> 3;

  const int g = l >> 4, c = l & 15;
  const int rr0 = l >> 3, rch = l & 7;

  __shared__ u16 Vl[64 * 72];
  __shared__ u16 Pl[64 * 72];

  auto pixof = [&](int a, int b2) -> int {
    int y = wi * 8 + a + 4; if (y >= 224) y -= 224;
    int x = wj * 8 + b2 + 4; if (x >= 224) x -= 224;
    return (bi * 224 + y) * 224 + x;
  };

  int pixr[4]; float svr[4], scr[4];
#pragma unroll
  for (int r = 0; r < 4; ++r) {
    const int p = r * 16 + c;
    pixr[r] = pixof(p >> 3, p & 7);
    svr[r] = sv[pixr[r]];
    scr[r] = sc[pixr[r]];
  }

  u16x8 vreg[8]; float vs_[8];
#pragma unroll
  for (int i = 0; i < 8; ++i) {
    const int pix = pixof(i, rr0);
    vs_[i] = sv[pix];
    vreg[i] = *(const u16x8*)(Pv + (size_t)pix * 1536 + 1024 + n * 64 + rch * 8);
  }

  f32x4 acc[4][4] = {};
#pragma unroll
  for (int kk = 0; kk < 2; ++kk) {
    const int e0 = kk * 32 + g * 8;
    const f8 qA = ld8(gAv + n * 64 + e0), qB = ld8(gBv + n * 64 + e0);
    const f8 kA = ld8(gAv + 512 + n * 64 + e0), kB = ld8(gBv + 512 + n * 64 + e0);
    bf16x8 af[4], bq[4];
#pragma unroll
    for (int r = 0; r < 4; ++r) {
      const u16* src = Pv + (size_t)pixr[r] * 1536 + n * 64 + e0;
      af[r] = nfrag(*(const u16x8*)(src + 512), kA, kB, svr[r]);
      bq[r] = nfrag(*(const u16x8*)src, qA, qB, svr[r]);
    }
#pragma unroll
    for (int mi = 0; mi < 4; ++mi)
#pragma unroll
      for (int ni = 0; ni < 4; ++ni)
        acc[mi][ni] = __builtin_amdgcn_mfma_f32_16x16x32_bf16(af[mi], bq[ni], acc[mi][ni], 0, 0, 0);
  }
#pragma unroll
  for (int kk = 0; kk < 2; ++kk) {
    const int e0 = kk * 32 + g * 8;
    const f8 qA = ld8(gAc + n * 64 + e0);
    const f8 kA = ld8(gAc + 512 + n * 64 + e0);
    bf16x8 af[4], bq[4];
#pragma unroll
    for (int r = 0; r < 4; ++r) {
      const u16* src = Pc + (size_t)pixr[r] * 1024 + n * 64 + e0;
      af[r] = nfragA(*(const u16x8*)(src + 512), kA, scr[r]);
      bq[r] = nfragA(*(const u16x8*)src, qA, scr[r]);
    }
#pragma unroll
    for (int mi = 0; mi < 4; ++mi)
#pragma unroll
      for (int ni = 0; ni < 4; ++ni)
        acc[mi][ni] = __builtin_amdgcn_mfma_f32_16x16x32_bf16(af[mi], bq[ni], acc[mi][ni], 0, 0, 0);
  }

  const int variant = ((wi == 27) ? 1 : 0) | ((wj == 27) ? 2 : 0);
  const float* BT = biasT + variant * 4096;
#pragma unroll
  for (int mi = 0; mi < 4; ++mi)
#pragma unroll
    for (int ni = 0; ni < 4; ++ni)
#pragma unroll
      for (int r = 0; r < 4; ++r) {
        const int q = mi * 16 + g * 4 + r;
        const int p = ni * 16 + c;
        acc[mi][ni][r] = acc[mi][ni][r] * 0.125f + BT[q * 64 + p];
      }
  float rinv[4];
#pragma unroll
  for (int ni = 0; ni < 4; ++ni) {
    float m = -3.0e38f;
#pragma unroll
    for (int mi = 0; mi < 4; ++mi)
#pragma unroll
      for (int r = 0; r < 4; ++r) m = fmaxf(m, acc[mi][ni][r]);
    m = fmaxf(m, __shfl_xor(m, 16));
    m = fmaxf(m, __shfl_xor(m, 32));
    float ssum = 0.f;
#pragma unroll
    for (int mi = 0; mi < 4; ++mi)
#pragma unroll
      for (int r = 0; r < 4; ++r) {
        float e = __expf(acc[mi][ni][r] - m);
        acc[mi][ni][r] = e;
        ssum += e;
      }
    ssum += __shfl_xor(ssum, 16);
    ssum += __shfl_xor(ssum, 32);
    rinv[ni] = 1.f / ssum;
  }

#pragma unroll
  for (int mi = 0; mi < 4; ++mi)
#pragma unroll
    for (int ni = 0; ni < 4; ++ni) {
      u16x4 pk;
#pragma unroll
      for (int r = 0; r < 4; ++r) pk[r] = f2bf(acc[mi][ni][r] * rinv[ni]);
      *(u16x4*)(Pl + (ni * 16 + c) * 72 + mi * 16 + g * 4) = pk;
    }
  {
    const f8 vA = ld8(gAv + 1024 + n * 64 + rch * 8);
    const f8 vB = ld8(gBv + 1024 + n * 64 + rch * 8);
#pragma unroll
    for (int i = 0; i < 8; ++i) {
      bf16x8 nv = nfrag(vreg[i], vA, vB, vs_[i]);
      *(bf16x8*)(Vl + (i * 8 + rr0) * 72 + rch * 8) = nv;
    }
  }

  f32x4 ya[4][4] = {};
#pragma unroll
  for (int kk = 0; kk < 2; ++kk) {
    bf16x8 pa[4];
#pragma unroll
    for (int mi = 0; mi < 4; ++mi)
      pa[mi] = *(const bf16x8*)(Pl + (mi * 16 + c) * 72 + kk * 32 + g * 8);
#pragma unroll
    for (int ni = 0; ni < 4; ++ni) {
      u16x8 vtmp;
#pragma unroll
      for (int j = 0; j < 8; ++j)
        vtmp[j] = Vl[(kk * 32 + g * 8 + j) * 72 + ni * 16 + c];
      bf16x8 vb = *(bf16x8*)&vtmp;
#pragma unroll
      for (int mi = 0; mi < 4; ++mi)
        ya[mi][ni] = __builtin_amdgcn_mfma_f32_16x16x32_bf16(pa[mi], vb, ya[mi][ni], 0, 0, 0);
    }
  }

  u16* Yt = Pl;
#pragma unroll
  for (int mi = 0; mi < 4; ++mi)
#pragma unroll
    for (int ni = 0; ni < 4; ++ni) {
      u16x4 yk;
#pragma unroll
      for (int r = 0; r < 4; ++r) yk[r] = f2bf(ya[mi][ni][r]);
      *(u16x4*)(Yt + (ni * 16 + c) * 72 + mi * 16 + g * 4) = yk;
    }
#pragma unroll
  for (int it = 0; it < 8; ++it) {
    const int b2 = l >> 3;
    const int ch = l & 7;
    const int p = it * 8 + b2;
    u16x8 row;
#pragma unroll
    for (int j = 0; j < 8; ++j) row[j] = Yt[(ch * 8 + j) * 72 + p];
    const int oy = wi * 8 + it, ox = wj * 8 + b2;
    *(u16x8*)(Y + ((size_t)(bi * 224 + oy) * 224 + ox) * 512 + n * 64 + ch * 8) = row;
  }
}

// ---------------------------------------------------------------------------
extern "C" void kernel_launch(void* const* d_in, const int* in_sizes, int n_in,
                              void* d_out, int out_size, void* d_ws, size_t ws_size,
                              hipStream_t stream) {
  const float* ev   = (const float*)d_in[0];
  const float* ec   = (const float*)d_in[1];
  const float* Wqkv = (const float*)d_in[2];
  const float* bqkv = (const float*)d_in[3];
  const float* g_v  = (const float*)d_in[4];
  const float* Wv   = (const float*)d_in[5];
  const float* bv   = (const float*)d_in[6];
  const float* Wqkc = (const float*)d_in[7];
  const float* bqkc = (const float*)d_in[8];
  const float* g_c  = (const float*)d_in[9];
  const float* pe   = (const float*)d_in[10];
  const float* Wout = (const float*)d_in[11];
  const float* bout = (const float*)d_in[12];
  float* out = (float*)d_out;

  char* w = (char*)d_ws;
  auto take = [&](size_t b) { char* p = w; w += (b + 255) & ~(size_t)255; return p; };
  u16* Wvp   = (u16*)take(1536ull * 512 * 2);
  u16* Wcp   = (u16*)take(1024ull * 128 * 2);
  u16* Wob   = (u16*)take(512ull * 512 * 2);
  float* bpv = (float*)take(1536 * 4);
  float* gAv = (float*)take(1536 * 4);
  float* gBv = (float*)take(1536 * 4);
  float* bpc = (float*)take(1024 * 4);
  float* gAc = (float*)take(1024 * 4);
  float* gBc = (float*)take(1024 * 4);
  float* bT  = (float*)take(4 * 4096 * 4);
  u16* Pv    = (u16*)take(100352ull * 1536 * 2);
  u16* Pc    = (u16*)take(100352ull * 1024 * 2);
  float* pvp = (float*)take(100352ull * 6 * 4);
  float* pcp = (float*)take(100352ull * 4 * 4);
  float* sv  = (float*)take(100352ull * 4);
  float* sc  = (float*)take(100352ull * 4);
  u16* Yb    = (u16*)take(100352ull * 512 * 2);
  u16* evb   = Yb;   // alias: evb dead before attn writes Yb
  u16* ecb   = (u16*)take(100352ull * 128 * 2);

  conv_bf16<<<25088, 256, 0, stream>>>(ev, evb);
  conv_bf16<<<6272, 256, 0, stream>>>(ec, ecb);
  prep_wv<<<3072, 256, 0, stream>>>(Wqkv, Wv, Wvp);
  prep_wc<<<512, 256, 0, stream>>>(Wqkc, Wcp);
  prep_wout<<<1024, 256, 0, stream>>>(Wout, Wob);
  prep_vec<<<6, 256, 0, stream>>>(bqkv, g_v, bv, bqkc, g_c, bpv, gAv, gBv, bpc, gAc, gBc);
  prep_biasT<<<64, 256, 0, stream>>>(pe, bT);

  gemm_bt<1536, 512, 0><<<2352, 512, 0, stream>>>(evb, Wvp, bpv, Pv, pvp, gBv, 2352);
  gemm_bt<1024, 128, 0><<<1568, 512, 0, stream>>>(ecb, Wcp, bpc, Pc, pcp, gBc, 1568);
  combine_scales<<<392, 256, 0, stream>>>(pvp, pcp, sv, sc);
  attn_kernel<<<12544, 64, 0, stream>>>(Pv, Pc, sv, sc, gAv, gBv, gAc, gBc, bT, Yb);
  gemm_bt<512, 512, 1><<<784, 512, 0, stream>>>(Yb, Wob, bout, out, nullptr, nullptr, 784);
}

// Round 12
// 739.472 us; speedup vs baseline: 1.1445x; 1.1445x over previous
//
#include <hip/hip_runtime.h>

// ---------------------------------------------------------------------------
// SeparateWindowedValuesCoordinatesAttention  (B=2, H=W=224, VD=512, CD=128,
// INNER=512, NH=8, E=64, WS=8, Wh=Ww=28; no padding since 224%8==0)
//
// R12: GEMM = m97 cell (128x128 tile, 4 waves, BK=64, SINGLE 32 KB LDS
// buffer, stage -> sync -> 32 MFMA -> sync) + the two post-R2 fixes:
//  - XCD swizzle (FETCH 408->72 MB, verified R7)
//  - bank-correct XOR for 128-B rows: chunk' = (4kk+g) ^ (c&7)
//    (row term == 0 mod 8 at 128-B rows, so R7's (c>>1)&3 only spreads 4 of
//     8 bank groups -> R10's 1.4e7 conflicts; c&7 spreads all 8, 2-way free)
// ~50% occupancy (vs R7 43%). attn unchanged from R9.
// ---------------------------------------------------------------------------

using u16 = unsigned short;
typedef short bf16x8 __attribute__((ext_vector_type(8)));   // MFMA A/B frag (8 bf16)
typedef float f32x4 __attribute__((ext_vector_type(4)));    // MFMA C/D frag
typedef u16 u16x4 __attribute__((ext_vector_type(4)));
typedef u16 u16x8 __attribute__((ext_vector_type(8)));

__device__ __forceinline__ float bf2f(u16 v) {
  return __uint_as_float(((unsigned)v) << 16);
}
__device__ __forceinline__ u16 f2bf(float f) {   // round-to-nearest-even
  unsigned u = __float_as_uint(f);
  u += 0x7fffu + ((u >> 16) & 1u);
  return (u16)(u >> 16);
}

// async global->LDS, 16 bytes per lane.
__device__ __forceinline__ void gld16(const u16* g, u16* l) {
  __builtin_amdgcn_global_load_lds(
      (const __attribute__((address_space(1))) unsigned*)g,
      (__attribute__((address_space(3))) unsigned*)l, 16, 0, 0);
}

struct f8 { float v[8]; };
__device__ __forceinline__ f8 ld8(const float* p) {
  f8 r;
  *(float4*)&r.v[0] = *(const float4*)p;
  *(float4*)&r.v[4] = *(const float4*)(p + 4);
  return r;
}
__device__ __forceinline__ bf16x8 nfrag(u16x8 raw, const f8& A, const f8& B, float s) {
  u16x8 o;
#pragma unroll
  for (int j = 0; j < 8; ++j) o[j] = f2bf(bf2f(raw[j]) * (A.v[j] * s + B.v[j]));
  return *(bf16x8*)&o;
}
__device__ __forceinline__ bf16x8 nfragA(u16x8 raw, const f8& A, float s) {
  u16x8 o;
#pragma unroll
  for (int j = 0; j < 8; ++j) o[j] = f2bf(bf2f(raw[j]) * (A.v[j] * s));
  return *(bf16x8*)&o;
}

// ---------------------------------------------------------------------------
// prep kernels
// ---------------------------------------------------------------------------
__global__ void conv_bf16(const float* __restrict__ in, u16* __restrict__ out) {
  size_t i = ((size_t)blockIdx.x * 256 + threadIdx.x) * 8;
  float4 a = *(const float4*)(in + i);
  float4 b = *(const float4*)(in + i + 4);
  u16x8 o;
  o[0] = f2bf(a.x); o[1] = f2bf(a.y); o[2] = f2bf(a.z); o[3] = f2bf(a.w);
  o[4] = f2bf(b.x); o[5] = f2bf(b.y); o[6] = f2bf(b.z); o[7] = f2bf(b.w);
  *(u16x8*)(out + i) = o;
}

__global__ void prep_wv(const float* __restrict__ Wqkv, const float* __restrict__ Wv,
                        u16* __restrict__ out) {
  int idx = blockIdx.x * 256 + threadIdx.x;
  if (idx >= 1536 * 512) return;
  int j = idx >> 9, kk = idx & 511;
  int t = j >> 9, rr = j & 511, nn = rr >> 6, e = rr & 63;
  int cc = 3 * (e * 8 + nn) + t;
  float v = (cc < 1024) ? Wqkv[kk * 1024 + cc] : Wv[kk * 512 + (cc - 1024)];
  out[idx] = f2bf(v);
}

__global__ void prep_wc(const float* __restrict__ W, u16* __restrict__ out) {
  int idx = blockIdx.x * 256 + threadIdx.x;
  if (idx >= 1024 * 128) return;
  int j = idx >> 7, kk = idx & 127;
  int t = j >> 9, rr = j & 511, nn = rr >> 6, e = rr & 63;
  int cc = 2 * (e * 8 + nn) + t;
  out[idx] = f2bf(W[kk * 1024 + cc]);
}

__global__ void prep_wout(const float* __restrict__ W, u16* __restrict__ out) {
  int idx = blockIdx.x * 256 + threadIdx.x;
  if (idx >= 512 * 512) return;
  int o = idx >> 9, kk = idx & 511;
  out[idx] = f2bf(W[kk * 512 + o]);
}

__global__ void prep_vec(const float* __restrict__ bqkv, const float* __restrict__ g_v,
                         const float* __restrict__ bv, const float* __restrict__ bqkc,
                         const float* __restrict__ g_c,
                         float* __restrict__ bpv, float* __restrict__ gAv, float* __restrict__ gBv,
                         float* __restrict__ bpc, float* __restrict__ gAc, float* __restrict__ gBc) {
  int j = blockIdx.x * 256 + threadIdx.x;
  if (j < 1536) {
    int t = j >> 9, rr = j & 511, nn = rr >> 6, e = rr & 63;
    int cc = 3 * (e * 8 + nn) + t;
    if (cc < 1024) { bpv[j] = bqkv[cc]; gAv[j] = g_v[cc]; gBv[j] = 0.f; }
    else           { bpv[j] = bv[cc - 1024]; gAv[j] = 0.f; gBv[j] = 1.f; }
  }
  if (j < 1024) {
    int t = j >> 9, rr = j & 511, nn = rr >> 6, e = rr & 63;
    int cc = 2 * (e * 8 + nn) + t;
    bpc[j] = bqkc[cc]; gAc[j] = g_c[cc]; gBc[j] = 0.f;
  }
}

__global__ void prep_biasT(const float* __restrict__ pe, float* __restrict__ bT) {
  int idx = blockIdx.x * 256 + threadIdx.x;
  if (idx >= 4 * 4096) return;
  int v = idx >> 12, q = (idx >> 6) & 63, p = idx & 63;
  int ap = p >> 3, bp = p & 7, aq = q >> 3, bq = q & 7;
  float val = pe[(aq - ap + 7) * 15 + (bq - bp + 7)];
  if ((v & 1) && ((ap >= 4) != (aq >= 4))) val = -1e30f;   // ROW_MASK (wi==27)
  if ((v & 2) && ((bp >= 4) != (bq >= 4))) val = -1e30f;   // COL_MASK (wj==27)
  bT[idx] = val;
}

// ---------------------------------------------------------------------------
// GEMM: C[M=100352][N] = A[M][K] * Bt[N][K]^T + bias   (A, Bt both bf16)
// m97 cell: 128x128 tile, 4 waves (2x2) each 64x64, BK=64, SINGLE 32 KB
// buffer: stage(kt) -> sync -> 2x(read frags, 16 MFMA) -> sync.
// LDS [128 rows][64 u16] (128-B rows, 8 chunks of 16 B); physical chunk
// p = q ^ (row & 7)  (q = logical chunk) -> frag reads hit all 8 bank
// groups 2-way (free). Staged via inverse-swizzled global source.
// 1D grid + bijective XCD swizzle. Lane (g,c), frag (mi,ni), reg r holds
//   C[rowbase + mi*16 + c][colbase + ni*16 + g*4 + r]
// MODE 0: bf16 out + sumsq partials.  MODE 1: f32 out.
// ---------------------------------------------------------------------------
template<int N, int K, int MODE>
__global__ __launch_bounds__(256) void gemm_bt(
    const u16* __restrict__ A, const u16* __restrict__ Bt,
    const float* __restrict__ bias, void* __restrict__ outp,
    float* __restrict__ part, const float* __restrict__ gB, int nwg) {
  constexpr int NCB = N / 128;
  constexpr int KT = K / 64;
  const int orig = blockIdx.x;
  const int work = (orig & 7) * (nwg >> 3) + (orig >> 3);
  const int bm = work / NCB, bn = work % NCB;

  const int tid = threadIdx.x;
  const int w = tid >> 6;
  const int lane = tid & 63;
  const int wr = w >> 1, wc = w & 1;
  const int g = lane >> 4, c = lane & 15;

  __shared__ u16 As[128 * 64];   // [row][chunk-swizzled 64 u16]  16 KB
  __shared__ u16 Bs[128 * 64];   // 16 KB

  f32x4 acc[4][4] = {};
  const u16* Ag = A + (size_t)bm * 128 * K;
  const u16* Bg = Bt + (size_t)bn * 128 * K;

  auto stage = [&](int kt) {     // 8 gld16 per thread (4 A + 4 B)
    const int k0 = kt * 64;
#pragma unroll
    for (int i = 0; i < 4; ++i) {
      const int idx = i * 256 + tid;            // 0..1023
      const int row = idx >> 3, p = idx & 7;
      const int q = p ^ (row & 7);              // inverse-swizzled source chunk
      gld16(Ag + (size_t)row * K + k0 + q * 8, As + idx * 8);
      gld16(Bg + (size_t)row * K + k0 + q * 8, Bs + idx * 8);
    }
  };

  const int cm = c & 7;          // row&7 for row = base16 + c
  for (int kt = 0; kt < KT; ++kt) {
    stage(kt);
    __syncthreads();             // vmcnt drained by compiler before barrier
#pragma unroll
    for (int kk = 0; kk < 2; ++kk) {
      bf16x8 af[4], bfv[4];
#pragma unroll
      for (int mi = 0; mi < 4; ++mi)
        af[mi] = *(const bf16x8*)(As + (wr * 64 + mi * 16 + c) * 64 +
                                  ((4 * kk + g) ^ cm) * 8);
#pragma unroll
      for (int ni = 0; ni < 4; ++ni)
        bfv[ni] = *(const bf16x8*)(Bs + (wc * 64 + ni * 16 + c) * 64 +
                                   ((4 * kk + g) ^ cm) * 8);
#pragma unroll
      for (int mi = 0; mi < 4; ++mi)
#pragma unroll
        for (int ni = 0; ni < 4; ++ni)
          acc[mi][ni] = __builtin_amdgcn_mfma_f32_16x16x32_bf16(bfv[ni], af[mi], acc[mi][ni], 0, 0, 0);
    }
    __syncthreads();             // WAR: all reads done before next stage
  }

  const int rowbase = bm * 128 + wr * 64;
  const int colbase = bn * 128 + wc * 64;
  if constexpr (MODE == 0) {
    u16* O = (u16*)outp;
    float rowsq[4] = {0.f, 0.f, 0.f, 0.f};   // row = rowbase + mi*16 + c
#pragma unroll
    for (int ni = 0; ni < 4; ++ni) {
      const int col4 = colbase + ni * 16 + g * 4;
      const float4 bb = *(const float4*)(bias + col4);
      const float4 gb = *(const float4*)(gB + col4);
#pragma unroll
      for (int mi = 0; mi < 4; ++mi) {
        const int row = rowbase + mi * 16 + c;
        u16x4 pk;
        float v0 = acc[mi][ni][0] + bb.x;
        float v1 = acc[mi][ni][1] + bb.y;
        float v2 = acc[mi][ni][2] + bb.z;
        float v3 = acc[mi][ni][3] + bb.w;
        pk[0] = f2bf(v0); pk[1] = f2bf(v1); pk[2] = f2bf(v2); pk[3] = f2bf(v3);
        *(u16x4*)(O + (size_t)row * N + col4) = pk;
        rowsq[mi] += (gb.x == 0.f ? v0 * v0 : 0.f) + (gb.y == 0.f ? v1 * v1 : 0.f)
                   + (gb.z == 0.f ? v2 * v2 : 0.f) + (gb.w == 0.f ? v3 * v3 : 0.f);
      }
    }
#pragma unroll
    for (int mi = 0; mi < 4; ++mi) {
      float s = rowsq[mi];
      s += __shfl_xor(s, 16);
      s += __shfl_xor(s, 32);
      rowsq[mi] = s;
    }
    float* red = (float*)As;   // K-loop ended with __syncthreads -> LDS free
    if (g == 0) {
#pragma unroll
      for (int mi = 0; mi < 4; ++mi)
        red[wc * 128 + wr * 64 + mi * 16 + c] = rowsq[mi];
    }
    __syncthreads();
    if (tid < 128)
      part[(size_t)(bm * 128 + tid) * NCB + bn] = red[tid] + red[128 + tid];
  } else {
    float* O = (float*)outp;
#pragma unroll
    for (int ni = 0; ni < 4; ++ni) {
      const int col4 = colbase + ni * 16 + g * 4;
      const float4 bb = *(const float4*)(bias + col4);
#pragma unroll
      for (int mi = 0; mi < 4; ++mi) {
        const int row = rowbase + mi * 16 + c;
        f32x4 o;
        o[0] = acc[mi][ni][0] + bb.x;
        o[1] = acc[mi][ni][1] + bb.y;
        o[2] = acc[mi][ni][2] + bb.z;
        o[3] = acc[mi][ni][3] + bb.w;
        *(f32x4*)(O + (size_t)row * N + col4) = o;
      }
    }
  }
}

// ---------------------------------------------------------------------------
__global__ void combine_scales(const float* __restrict__ pvp, const float* __restrict__ pcp,
                               float* __restrict__ sv, float* __restrict__ sc) {
  const int i = blockIdx.x * 256 + threadIdx.x;  // exact 100352
  float s = 0.f;
#pragma unroll
  for (int k = 0; k < 12; ++k) s += pvp[(size_t)i * 12 + k];
  sv[i] = rsqrtf(s * (1.f / 1024.f) + 1e-6f);
  float s2 = 0.f;
#pragma unroll
  for (int k = 0; k < 8; ++k) s2 += pcp[(size_t)i * 8 + k];
  sc[i] = rsqrtf(s2 * (1.f / 1024.f) + 1e-6f);
}

// ---------------------------------------------------------------------------
// attention (unchanged from R9): one wave per (batch, head, window);
// K/Q fragments direct from global with inline rmsnorm; LDS only for P and V.
// ---------------------------------------------------------------------------
__global__ __launch_bounds__(64) void attn_kernel(
    const u16* __restrict__ Pv, const u16* __restrict__ Pc,
    const float* __restrict__ sv, const float* __restrict__ sc,
    const float* __restrict__ gAv, const float* __restrict__ gBv,
    const float* __restrict__ gAc, const float* __restrict__ gBc,
    const float* __restrict__ biasT, u16* __restrict__ Y) {
  const int l = threadIdx.x;
  int bx = blockIdx.x;
  const int wj = bx % 28; bx /= 28;
  const int wi = bx % 28; bx /= 28;
  const int n = bx & 7;
  const int bi = bx >> 3;

  const int g = l >> 4, c = l & 15;
  const int rr0 = l >> 3, rch = l & 7;

  __shared__ u16 Vl[64 * 72];
  __shared__ u16 Pl[64 * 72];

  auto pixof = [&](int a, int b2) -> int {
    int y = wi * 8 + a + 4; if (y >= 224) y -= 224;
    int x = wj * 8 + b2 + 4; if (x >= 224) x -= 224;
    return (bi * 224 + y) * 224 + x;
  };

  int pixr[4]; float svr[4], scr[4];
#pragma unroll
  for (int r = 0; r < 4; ++r) {
    const int p = r * 16 + c;
    pixr[r] = pixof(p >> 3, p & 7);
    svr[r] = sv[pixr[r]];
    scr[r] = sc[pixr[r]];
  }

  u16x8 vreg[8]; float vs_[8];
#pragma unroll
  for (int i = 0; i < 8; ++i) {
    const int pix = pixof(i, rr0);
    vs_[i] = sv[pix];
    vreg[i] = *(const u16x8*)(Pv + (size_t)pix * 1536 + 1024 + n * 64 + rch * 8);
  }

  f32x4 acc[4][4] = {};
#pragma unroll
  for (int kk = 0; kk < 2; ++kk) {
    const int e0 = kk * 32 + g * 8;
    const f8 qA = ld8(gAv + n * 64 + e0), qB = ld8(gBv + n * 64 + e0);
    const f8 kA = ld8(gAv + 512 + n * 64 + e0), kB = ld8(gBv + 512 + n * 64 + e0);
    bf16x8 af[4], bq[4];
#pragma unroll
    for (int r = 0; r < 4; ++r) {
      const u16* src = Pv + (size_t)pixr[r] * 1536 + n * 64 + e0;
      af[r] = nfrag(*(const u16x8*)(src + 512), kA, kB, svr[r]);
      bq[r] = nfrag(*(const u16x8*)src, qA, qB, svr[r]);
    }
#pragma unroll
    for (int mi = 0; mi < 4; ++mi)
#pragma unroll
      for (int ni = 0; ni < 4; ++ni)
        acc[mi][ni] = __builtin_amdgcn_mfma_f32_16x16x32_bf16(af[mi], bq[ni], acc[mi][ni], 0, 0, 0);
  }
#pragma unroll
  for (int kk = 0; kk < 2; ++kk) {
    const int e0 = kk * 32 + g * 8;
    const f8 qA = ld8(gAc + n * 64 + e0);
    const f8 kA = ld8(gAc + 512 + n * 64 + e0);
    bf16x8 af[4], bq[4];
#pragma unroll
    for (int r = 0; r < 4; ++r) {
      const u16* src = Pc + (size_t)pixr[r] * 1024 + n * 64 + e0;
      af[r] = nfragA(*(const u16x8*)(src + 512), kA, scr[r]);
      bq[r] = nfragA(*(const u16x8*)src, qA, scr[r]);
    }
#pragma unroll
    for (int mi = 0; mi < 4; ++mi)
#pragma unroll
      for (int ni = 0; ni < 4; ++ni)
        acc[mi][ni] = __builtin_amdgcn_mfma_f32_16x16x32_bf16(af[mi], bq[ni], acc[mi][ni], 0, 0, 0);
  }

  const int variant = ((wi == 27) ? 1 : 0) | ((wj == 27) ? 2 : 0);
  const float* BT = biasT + variant * 4096;
#pragma unroll
  for (int mi = 0; mi < 4; ++mi)
#pragma unroll
    for (int ni = 0; ni < 4; ++ni)
#pragma unroll
      for (int r = 0; r < 4; ++r) {
        const int q = mi * 16 + g * 4 + r;
        const int p = ni * 16 + c;
        acc[mi][ni][r] = acc[mi][ni][r] * 0.125f + BT[q * 64 + p];
      }
  float rinv[4];
#pragma unroll
  for (int ni = 0; ni < 4; ++ni) {
    float m = -3.0e38f;
#pragma unroll
    for (int mi = 0; mi < 4; ++mi)
#pragma unroll
      for (int r = 0; r < 4; ++r) m = fmaxf(m, acc[mi][ni][r]);
    m = fmaxf(m, __shfl_xor(m, 16));
    m = fmaxf(m, __shfl_xor(m, 32));
    float ssum = 0.f;
#pragma unroll
    for (int mi = 0; mi < 4; ++mi)
#pragma unroll
      for (int r = 0; r < 4; ++r) {
        float e = __expf(acc[mi][ni][r] - m);
        acc[mi][ni][r] = e;
        ssum += e;
      }
    ssum += __shfl_xor(ssum, 16);
    ssum += __shfl_xor(ssum, 32);
    rinv[ni] = 1.f / ssum;
  }

#pragma unroll
  for (int mi = 0; mi < 4; ++mi)
#pragma unroll
    for (int ni = 0; ni < 4; ++ni) {
      u16x4 pk;
#pragma unroll
      for (int r = 0; r < 4; ++r) pk[r] = f2bf(acc[mi][ni][r] * rinv[ni]);
      *(u16x4*)(Pl + (ni * 16 + c) * 72 + mi * 16 + g * 4) = pk;
    }
  {
    const f8 vA = ld8(gAv + 1024 + n * 64 + rch * 8);
    const f8 vB = ld8(gBv + 1024 + n * 64 + rch * 8);
#pragma unroll
    for (int i = 0; i < 8; ++i) {
      bf16x8 nv = nfrag(vreg[i], vA, vB, vs_[i]);
      *(bf16x8*)(Vl + (i * 8 + rr0) * 72 + rch * 8) = nv;
    }
  }

  f32x4 ya[4][4] = {};
#pragma unroll
  for (int kk = 0; kk < 2; ++kk) {
    bf16x8 pa[4];
#pragma unroll
    for (int mi = 0; mi < 4; ++mi)
      pa[mi] = *(const bf16x8*)(Pl + (mi * 16 + c) * 72 + kk * 32 + g * 8);
#pragma unroll
    for (int ni = 0; ni < 4; ++ni) {
      u16x8 vtmp;
#pragma unroll
      for (int j = 0; j < 8; ++j)
        vtmp[j] = Vl[(kk * 32 + g * 8 + j) * 72 + ni * 16 + c];
      bf16x8 vb = *(bf16x8*)&vtmp;
#pragma unroll
      for (int mi = 0; mi < 4; ++mi)
        ya[mi][ni] = __builtin_amdgcn_mfma_f32_16x16x32_bf16(pa[mi], vb, ya[mi][ni], 0, 0, 0);
    }
  }

  u16* Yt = Pl;
#pragma unroll
  for (int mi = 0; mi < 4; ++mi)
#pragma unroll
    for (int ni = 0; ni < 4; ++ni) {
      u16x4 yk;
#pragma unroll
      for (int r = 0; r < 4; ++r) yk[r] = f2bf(ya[mi][ni][r]);
      *(u16x4*)(Yt + (ni * 16 + c) * 72 + mi * 16 + g * 4) = yk;
    }
#pragma unroll
  for (int it = 0; it < 8; ++it) {
    const int b2 = l >> 3;
    const int ch = l & 7;
    const int p = it * 8 + b2;
    u16x8 row;
#pragma unroll
    for (int j = 0; j < 8; ++j) row[j] = Yt[(ch * 8 + j) * 72 + p];
    const int oy = wi * 8 + it, ox = wj * 8 + b2;
    *(u16x8*)(Y + ((size_t)(bi * 224 + oy) * 224 + ox) * 512 + n * 64 + ch * 8) = row;
  }
}

// ---------------------------------------------------------------------------
extern "C" void kernel_launch(void* const* d_in, const int* in_sizes, int n_in,
                              void* d_out, int out_size, void* d_ws, size_t ws_size,
                              hipStream_t stream) {
  const float* ev   = (const float*)d_in[0];
  const float* ec   = (const float*)d_in[1];
  const float* Wqkv = (const float*)d_in[2];
  const float* bqkv = (const float*)d_in[3];
  const float* g_v  = (const float*)d_in[4];
  const float* Wv   = (const float*)d_in[5];
  const float* bv   = (const float*)d_in[6];
  const float* Wqkc = (const float*)d_in[7];
  const float* bqkc = (const float*)d_in[8];
  const float* g_c  = (const float*)d_in[9];
  const float* pe   = (const float*)d_in[10];
  const float* Wout = (const float*)d_in[11];
  const float* bout = (const float*)d_in[12];
  float* out = (float*)d_out;

  char* w = (char*)d_ws;
  auto take = [&](size_t b) { char* p = w; w += (b + 255) & ~(size_t)255; return p; };
  u16* Wvp   = (u16*)take(1536ull * 512 * 2);
  u16* Wcp   = (u16*)take(1024ull * 128 * 2);
  u16* Wob   = (u16*)take(512ull * 512 * 2);
  float* bpv = (float*)take(1536 * 4);
  float* gAv = (float*)take(1536 * 4);
  float* gBv = (float*)take(1536 * 4);
  float* bpc = (float*)take(1024 * 4);
  float* gAc = (float*)take(1024 * 4);
  float* gBc = (float*)take(1024 * 4);
  float* bT  = (float*)take(4 * 4096 * 4);
  u16* Pv    = (u16*)take(100352ull * 1536 * 2);
  u16* Pc    = (u16*)take(100352ull * 1024 * 2);
  float* pvp = (float*)take(100352ull * 12 * 4);
  float* pcp = (float*)take(100352ull * 8 * 4);
  float* sv  = (float*)take(100352ull * 4);
  float* sc  = (float*)take(100352ull * 4);
  u16* Yb    = (u16*)take(100352ull * 512 * 2);
  u16* evb   = Yb;   // alias: evb dead before attn writes Yb
  u16* ecb   = (u16*)take(100352ull * 128 * 2);

  conv_bf16<<<25088, 256, 0, stream>>>(ev, evb);
  conv_bf16<<<6272, 256, 0, stream>>>(ec, ecb);
  prep_wv<<<3072, 256, 0, stream>>>(Wqkv, Wv, Wvp);
  prep_wc<<<512, 256, 0, stream>>>(Wqkc, Wcp);
  prep_wout<<<1024, 256, 0, stream>>>(Wout, Wob);
  prep_vec<<<6, 256, 0, stream>>>(bqkv, g_v, bv, bqkc, g_c, bpv, gAv, gBv, bpc, gAc, gBc);
  prep_biasT<<<64, 256, 0, stream>>>(pe, bT);

  gemm_bt<1536, 512, 0><<<9408, 256, 0, stream>>>(evb, Wvp, bpv, Pv, pvp, gBv, 9408);
  gemm_bt<1024, 128, 0><<<6272, 256, 0, stream>>>(ecb, Wcp, bpc, Pc, pcp, gBc, 6272);
  combine_scales<<<392, 256, 0, stream>>>(pvp, pcp, sv, sc);
  attn_kernel<<<12544, 64, 0, stream>>>(Pv, Pc, sv, sc, gAv, gBv, gAc, gBc, bT, Yb);
  gemm_bt<512, 512, 1><<<3136, 256, 0, stream>>>(Yb, Wob, bout, out, nullptr, nullptr, 3136);
}